// Round 1
// baseline (2147.632 us; speedup 1.0000x reference)
//
#include <hip/hip_runtime.h>

typedef unsigned short u16;
typedef __attribute__((ext_vector_type(8))) __bf16 bfrag;
typedef __attribute__((ext_vector_type(4))) float f32x4;

static __device__ __forceinline__ f32x4 MFMA(bfrag a, bfrag b, f32x4 c) {
  return __builtin_amdgcn_mfma_f32_16x16x32_bf16(a, b, c, 0, 0, 0);
}

// float -> bf16 (RNE)
static __device__ __forceinline__ u16 f2b(float f) {
  union { float f; unsigned u; } v; v.f = f;
  unsigned r = (v.u + 0x7fffu + ((v.u >> 16) & 1u)) >> 16;
  return (u16)r;
}
static __device__ __forceinline__ float ssig(float x) { return 1.f / (1.f + __expf(-x)); }
static __device__ __forceinline__ float stanh(float x) { return 1.f - 2.f / (__expf(2.f * x) + 1.f); }

// ---------------------------------------------------------------------------
// prep: bf16 casts + gate-reordered / combined decode weights
// gate reorder: n' = hcol*4 + gate  (gate 0..3 = i,f,g,o; source row = gate*H + hcol)
// ---------------------------------------------------------------------------
struct PrepArgs {
  const float *x, *W1, *W2, *W3, *Wh1, *Wc1, *Wx1, *Wh2, *Wc2, *Wx2;
  const float *rWih, *rWhh, *rbih, *rbhh, *pWih, *pWhh, *pbih, *pbhh;
  u16 *Xbf, *W1b, *W2b, *W3b, *Wh1b, *Wc1b, *Wx1b, *Wh2b, *Wc2b, *Wx2b;
  u16 *WcR, *WcatR, *pWR, *pWhhR;
  float *rbR, *pbR;
};

__global__ __launch_bounds__(256) void prep(PrepArgs p) {
  const int tid0 = blockIdx.x * 256 + threadIdx.x;
  const int stride = gridDim.x * 256;
  switch (blockIdx.y) {
    case 0: for (int i = tid0; i < 131072; i += stride) p.Xbf[i] = f2b(p.x[i]); break;
    case 1: for (int i = tid0; i < 65536;  i += stride) p.W1b[i] = f2b(p.W1[i]); break;
    case 2: for (int i = tid0; i < 262144; i += stride) p.W2b[i] = f2b(p.W2[i]); break;
    case 3: for (int i = tid0; i < 262144; i += stride) p.W3b[i] = f2b(p.W3[i]); break;
    case 4: for (int i = tid0; i < 262144; i += stride) p.Wh1b[i] = f2b(p.Wh1[i]); break;
    case 5: for (int i = tid0; i < 262144; i += stride) p.Wc1b[i] = f2b(p.Wc1[i]); break;
    case 6: for (int i = tid0; i < 262144; i += stride) p.Wx1b[i] = f2b(p.Wx1[i]); break;
    case 7: for (int i = tid0; i < 131072; i += stride) p.Wh2b[i] = f2b(p.Wh2[i]); break;
    case 8: for (int i = tid0; i < 131072; i += stride) p.Wc2b[i] = f2b(p.Wc2[i]); break;
    case 9: for (int i = tid0; i < 131072; i += stride) p.Wx2b[i] = f2b(p.Wx2[i]); break;
    case 10: // decode weights: combined (steps>=1) and concat (step 0), reordered
      for (int i = tid0; i < 262144; i += stride) {
        int n2 = i >> 8, k = i & 255;
        int srow = ((n2 & 3) << 8) + (n2 >> 2);
        float a = p.rWih[srow * 256 + k], b = p.rWhh[srow * 256 + k];
        p.WcR[i] = f2b(a + b);
        p.WcatR[n2 * 512 + k] = f2b(a);
        p.WcatR[n2 * 512 + 256 + k] = f2b(b);
      }
      break;
    case 11:
      for (int i = tid0; i < 1024; i += stride) {
        int srow = ((i & 3) << 8) + (i >> 2);
        p.rbR[i] = p.rbih[srow] + p.rbhh[srow];
      }
      break;
    case 12:
      for (int i = tid0; i < 32768; i += stride) {
        int n2 = i >> 8, k = i & 255;
        int srow = ((n2 & 3) << 5) + (n2 >> 2);
        p.pWR[i] = f2b(p.pWih[srow * 256 + k]);
      }
      break;
    case 13:
      for (int i = tid0; i < 4096; i += stride) {
        int n2 = i >> 5, k = i & 31;
        int srow = ((n2 & 3) << 5) + (n2 >> 2);
        p.pWhhR[i] = f2b(p.pWhh[srow * 32 + k]);
      }
      break;
    case 14:
      for (int i = tid0; i < 128; i += stride) {
        int srow = ((i & 3) << 5) + (i >> 2);
        p.pbR[i] = p.pbih[srow] + p.pbhh[srow];
      }
      break;
  }
}

// ---------------------------------------------------------------------------
// gemm_act: Y[1024,N] = act(X[1024,K] @ W[N,K]^T + bias), bf16 in, fp32 acc.
// grid (16, N/64), 256 thr; wave = 16 rows x 64 cols of the 64x64 block tile.
// ---------------------------------------------------------------------------
__global__ __launch_bounds__(256) void gemm_act(
    const u16* __restrict__ X, const u16* __restrict__ W,
    const float* __restrict__ bias,
    u16* __restrict__ Yb, float* __restrict__ Yf,
    int K, int ldo, int coloff, int leaky) {
  const int rt = blockIdx.x, ct = blockIdx.y;
  const int lane = threadIdx.x & 63, wave = threadIdx.x >> 6;
  const int m15 = lane & 15, q = lane >> 4, kq = q * 8;
  const int row = rt * 64 + wave * 16 + m15;
  f32x4 acc[4] = {};
  const u16* xp = X + (size_t)row * K + kq;
  for (int k0 = 0; k0 < K; k0 += 32) {
    bfrag a = *(const bfrag*)(xp + k0);
#pragma unroll
    for (int nt = 0; nt < 4; nt++) {
      const u16* wp = W + (size_t)(ct * 64 + nt * 16 + m15) * K + k0 + kq;
      acc[nt] = MFMA(a, *(const bfrag*)wp, acc[nt]);
    }
  }
#pragma unroll
  for (int nt = 0; nt < 4; nt++) {
    int col = ct * 64 + nt * 16 + m15;
    float bv = bias[col];
#pragma unroll
    for (int r = 0; r < 4; r++) {
      int orow = rt * 64 + wave * 16 + q * 4 + r;
      float v = acc[nt][r] + bv;
      if (leaky) v = v >= 0.f ? v : 0.2f * v;
      if (Yb) Yb[(size_t)orow * ldo + coloff + col] = f2b(v);
      else    Yf[(size_t)orow * ldo + coloff + col] = v;
    }
  }
}

// ---------------------------------------------------------------------------
// decode_step: gates = A[1024,K] @ W[1024,K]^T (gate-reordered cols) + rb,
// then LSTM update. grid (16 row tiles, 8 col groups of 128 gate cols = 32 h).
// C state fp32 in-place; Hout = bf16 h_t (also the outs[t] slot).
// ---------------------------------------------------------------------------
__global__ __launch_bounds__(256) void decode_step(
    const u16* __restrict__ A, const u16* __restrict__ W,
    const float* __restrict__ rb,
    float* __restrict__ C, u16* __restrict__ Hout, int K) {
  __shared__ float g[64][128];
  const int rt = blockIdx.x, cg = blockIdx.y;
  const int lane = threadIdx.x & 63, wave = threadIdx.x >> 6;
  const int m15 = lane & 15, q = lane >> 4, kq = q * 8;
  const int row = rt * 64 + wave * 16 + m15;
  f32x4 acc[8] = {};
  const u16* ap = A + (size_t)row * K + kq;
  for (int k0 = 0; k0 < K; k0 += 32) {
    bfrag a = *(const bfrag*)(ap + k0);
#pragma unroll
    for (int nt = 0; nt < 8; nt++) {
      const u16* wp = W + (size_t)(cg * 128 + nt * 16 + m15) * K + k0 + kq;
      acc[nt] = MFMA(a, *(const bfrag*)wp, acc[nt]);
    }
  }
#pragma unroll
  for (int nt = 0; nt < 8; nt++)
#pragma unroll
    for (int r = 0; r < 4; r++)
      g[wave * 16 + q * 4 + r][nt * 16 + m15] = acc[nt][r];
  __syncthreads();
  for (int t = threadIdx.x; t < 2048; t += 256) {
    int rl = t >> 5, hc = t & 31;
    int grow = rt * 64 + rl, gcol = cg * 32 + hc;
    float gi = g[rl][hc * 4 + 0] + rb[cg * 128 + hc * 4 + 0];
    float gf = g[rl][hc * 4 + 1] + rb[cg * 128 + hc * 4 + 1];
    float gg = g[rl][hc * 4 + 2] + rb[cg * 128 + hc * 4 + 2];
    float go = g[rl][hc * 4 + 3] + rb[cg * 128 + hc * 4 + 3];
    size_t ci = (size_t)grow * 256 + gcol;
    float c = C[ci];
    float cn = ssig(gf) * c + ssig(gi) * stanh(gg);
    float hn = ssig(go) * stanh(cn);
    C[ci] = cn;
    Hout[ci] = f2b(hn);
  }
}

// ---------------------------------------------------------------------------
// predictor: persistent; block = 8 batch rows, loops all 128 steps.
// Pred weights (gate-reordered) live in registers as B-fragments.
// Fused softmax(0..30)/sigmoid(31) epilogue writes d_out directly.
// ---------------------------------------------------------------------------
__global__ __launch_bounds__(256) void predictor(
    const u16* __restrict__ OUTS, const u16* __restrict__ pW,
    const u16* __restrict__ pWhh, const float* __restrict__ pb,
    float* __restrict__ out) {
  __shared__ __align__(16) u16 hs[8][32];
  __shared__ float gl[16][128];
  __shared__ float cs[8][32];
  __shared__ float ys[8][32];
  __shared__ float sm[8], sd[8];
  const int blk = blockIdx.x;
  const int tid = threadIdx.x;
  const int lane = tid & 63, wave = tid >> 6;
  const int m15 = lane & 15, q = lane >> 4, kq = q * 8;
  const int r8 = m15 & 7;

  bfrag WB[2][8], WH[2];
#pragma unroll
  for (int nt = 0; nt < 2; nt++) {
    int n = wave * 32 + nt * 16 + m15;
#pragma unroll
    for (int kt = 0; kt < 8; kt++)
      WB[nt][kt] = *(const bfrag*)(pW + (size_t)n * 256 + kt * 32 + kq);
    WH[nt] = *(const bfrag*)(pWhh + (size_t)n * 32 + kq);
  }
  hs[tid >> 5][tid & 31] = 0;
  cs[tid >> 5][tid & 31] = 0.f;
  __syncthreads();

  for (int s = 0; s < 128; s++) {
    const u16* Xs = OUTS + (size_t)s * 1024 * 256 + (size_t)(blk * 8 + r8) * 256 + kq;
    f32x4 a0 = {}, a1 = {};
#pragma unroll
    for (int kt = 0; kt < 8; kt++) {
      bfrag a = *(const bfrag*)(Xs + kt * 32);
      a0 = MFMA(a, WB[0][kt], a0);
      a1 = MFMA(a, WB[1][kt], a1);
    }
    bfrag ah = *(const bfrag*)(&hs[r8][kq]);
    a0 = MFMA(ah, WH[0], a0);
    a1 = MFMA(ah, WH[1], a1);
    __syncthreads();  // hs fully consumed, gl free
#pragma unroll
    for (int r = 0; r < 4; r++) {
      int rl = q * 4 + r;
      gl[rl][wave * 32 + m15]      = a0[r] + pb[wave * 32 + m15];
      gl[rl][wave * 32 + 16 + m15] = a1[r] + pb[wave * 32 + 16 + m15];
    }
    __syncthreads();
    {
      int r_ = tid >> 5, c_ = tid & 31;
      float gi = gl[r_][c_ * 4 + 0], gf = gl[r_][c_ * 4 + 1];
      float gg = gl[r_][c_ * 4 + 2], go = gl[r_][c_ * 4 + 3];
      float c = cs[r_][c_];
      float cn = ssig(gf) * c + ssig(gi) * stanh(gg);
      float hn = ssig(go) * stanh(cn);
      cs[r_][c_] = cn;
      hs[r_][c_] = f2b(hn);
      ys[r_][c_] = hn;
    }
    __syncthreads();
    if (tid < 8) {
      float m = ys[tid][0];
      for (int j = 1; j < 31; j++) m = fmaxf(m, ys[tid][j]);
      float ss = 0.f;
      for (int j = 0; j < 31; j++) ss += __expf(ys[tid][j] - m);
      sm[tid] = m; sd[tid] = ss;
    }
    __syncthreads();
    {
      int r_ = tid >> 5, c_ = tid & 31;
      float v = (c_ < 31) ? __expf(ys[r_][c_] - sm[r_]) / sd[r_] : ssig(ys[r_][31]);
      out[(size_t)(blk * 8 + r_) * 4096 + s * 32 + c_] = v;
    }
  }
}

// ---------------------------------------------------------------------------
extern "C" void kernel_launch(void* const* d_in, const int* in_sizes, int n_in,
                              void* d_out, int out_size, void* d_ws, size_t ws_size,
                              hipStream_t stream) {
  (void)in_sizes; (void)n_in; (void)out_size; (void)ws_size;
  const float* x    = (const float*)d_in[0];
  const float* W1   = (const float*)d_in[1];
  const float* b1   = (const float*)d_in[2];
  const float* W2   = (const float*)d_in[3];
  const float* b2   = (const float*)d_in[4];
  const float* W3   = (const float*)d_in[5];
  const float* b3   = (const float*)d_in[6];
  const float* Wh1  = (const float*)d_in[7];
  const float* bh1  = (const float*)d_in[8];
  const float* Wh2  = (const float*)d_in[9];
  const float* bh2  = (const float*)d_in[10];
  const float* Wc1  = (const float*)d_in[11];
  const float* bc1  = (const float*)d_in[12];
  const float* Wc2  = (const float*)d_in[13];
  const float* bc2  = (const float*)d_in[14];
  const float* Wx1  = (const float*)d_in[15];
  const float* bx1  = (const float*)d_in[16];
  const float* Wx2  = (const float*)d_in[17];
  const float* bx2  = (const float*)d_in[18];
  const float* rWih = (const float*)d_in[19];
  const float* rWhh = (const float*)d_in[20];
  const float* rbih = (const float*)d_in[21];
  const float* rbhh = (const float*)d_in[22];
  const float* pWih = (const float*)d_in[23];
  const float* pWhh = (const float*)d_in[24];
  const float* pbih = (const float*)d_in[25];
  const float* pbhh = (const float*)d_in[26];

  char* w = (char*)d_ws;
  auto alloc = [&](size_t bytes) -> char* {
    char* p = w;
    w += (bytes + 255) & ~(size_t)255;
    return p;
  };
  u16* Xbf  = (u16*)alloc(1024 * 128 * 2);
  u16* T1   = (u16*)alloc(1024 * 512 * 2);
  u16* T2   = (u16*)alloc(1024 * 512 * 2);
  u16* T3   = (u16*)alloc(1024 * 512 * 2);
  u16* TH   = (u16*)alloc(1024 * 512 * 2);
  u16* TC   = (u16*)alloc(1024 * 512 * 2);
  u16* TX   = (u16*)alloc(1024 * 512 * 2);
  u16* X0H  = (u16*)alloc(1024 * 512 * 2);  // cols 0..255 = x0, 256..511 = h
  float* CB = (float*)alloc(1024 * 256 * 4);
  u16* OUTS = (u16*)alloc((size_t)128 * 1024 * 256 * 2);
  u16* W1b  = (u16*)alloc(512 * 128 * 2);
  u16* W2b  = (u16*)alloc(512 * 512 * 2);
  u16* W3b  = (u16*)alloc(512 * 512 * 2);
  u16* Wh1b = (u16*)alloc(512 * 512 * 2);
  u16* Wc1b = (u16*)alloc(512 * 512 * 2);
  u16* Wx1b = (u16*)alloc(512 * 512 * 2);
  u16* Wh2b = (u16*)alloc(256 * 512 * 2);
  u16* Wc2b = (u16*)alloc(256 * 512 * 2);
  u16* Wx2b = (u16*)alloc(256 * 512 * 2);
  u16* WcR  = (u16*)alloc(1024 * 256 * 2);
  u16* WcatR= (u16*)alloc(1024 * 512 * 2);
  float* rbR = (float*)alloc(1024 * 4);
  u16* pWR  = (u16*)alloc(128 * 256 * 2);
  u16* pWhhR= (u16*)alloc(128 * 32 * 2);
  float* pbR = (float*)alloc(128 * 4);

  PrepArgs pa;
  pa.x = x; pa.W1 = W1; pa.W2 = W2; pa.W3 = W3; pa.Wh1 = Wh1; pa.Wc1 = Wc1; pa.Wx1 = Wx1;
  pa.Wh2 = Wh2; pa.Wc2 = Wc2; pa.Wx2 = Wx2;
  pa.rWih = rWih; pa.rWhh = rWhh; pa.rbih = rbih; pa.rbhh = rbhh;
  pa.pWih = pWih; pa.pWhh = pWhh; pa.pbih = pbih; pa.pbhh = pbhh;
  pa.Xbf = Xbf; pa.W1b = W1b; pa.W2b = W2b; pa.W3b = W3b; pa.Wh1b = Wh1b;
  pa.Wc1b = Wc1b; pa.Wx1b = Wx1b; pa.Wh2b = Wh2b; pa.Wc2b = Wc2b; pa.Wx2b = Wx2b;
  pa.WcR = WcR; pa.WcatR = WcatR; pa.pWR = pWR; pa.pWhhR = pWhhR;
  pa.rbR = rbR; pa.pbR = pbR;
  prep<<<dim3(32, 15), 256, 0, stream>>>(pa);

  // MLP + heads
  gemm_act<<<dim3(16, 8), 256, 0, stream>>>(Xbf, W1b, b1, T1, nullptr, 128, 512, 0, 1);
  gemm_act<<<dim3(16, 8), 256, 0, stream>>>(T1, W2b, b2, T2, nullptr, 512, 512, 0, 1);
  gemm_act<<<dim3(16, 8), 256, 0, stream>>>(T2, W3b, b3, T3, nullptr, 512, 512, 0, 1);
  gemm_act<<<dim3(16, 8), 256, 0, stream>>>(T3, Wh1b, bh1, TH, nullptr, 512, 512, 0, 1);
  gemm_act<<<dim3(16, 8), 256, 0, stream>>>(T3, Wc1b, bc1, TC, nullptr, 512, 512, 0, 1);
  gemm_act<<<dim3(16, 8), 256, 0, stream>>>(T3, Wx1b, bx1, TX, nullptr, 512, 512, 0, 1);
  gemm_act<<<dim3(16, 4), 256, 0, stream>>>(TH, Wh2b, bh2, X0H, nullptr, 512, 512, 256, 0); // h
  gemm_act<<<dim3(16, 4), 256, 0, stream>>>(TC, Wc2b, bc2, nullptr, CB, 512, 256, 0, 0);    // c (fp32)
  gemm_act<<<dim3(16, 4), 256, 0, stream>>>(TX, Wx2b, bx2, X0H, nullptr, 512, 512, 0, 0);   // x0

  // decode LSTM: step 0 uses concat(x0,h) @ concat(rWih,rWhh)^T; rest use combined W
  decode_step<<<dim3(16, 8), 256, 0, stream>>>(X0H, WcatR, rbR, CB, OUTS, 512);
  for (int s = 1; s < 128; s++)
    decode_step<<<dim3(16, 8), 256, 0, stream>>>(
        OUTS + (size_t)(s - 1) * 1024 * 256, WcR, rbR, CB,
        OUTS + (size_t)s * 1024 * 256, 256);

  // predictor LSTM + fused softmax/sigmoid epilogue
  predictor<<<128, 256, 0, stream>>>(OUTS, pWR, pWhhR, pbR, (float*)d_out);
}

// Round 3
// 1636.642 us; speedup vs baseline: 1.3122x; 1.3122x over previous
//
#include <hip/hip_runtime.h>

typedef unsigned short u16;
typedef __attribute__((ext_vector_type(8))) __bf16 bfrag;
typedef __attribute__((ext_vector_type(4))) float f32x4;

static __device__ __forceinline__ f32x4 MFMA(bfrag a, bfrag b, f32x4 c) {
  return __builtin_amdgcn_mfma_f32_16x16x32_bf16(a, b, c, 0, 0, 0);
}

// float -> bf16 (RNE)
static __device__ __forceinline__ u16 f2b(float f) {
  union { float f; unsigned u; } v; v.f = f;
  unsigned r = (v.u + 0x7fffu + ((v.u >> 16) & 1u)) >> 16;
  return (u16)r;
}
static __device__ __forceinline__ float ssig(float x) { return 1.f / (1.f + __expf(-x)); }
static __device__ __forceinline__ float stanh(float x) { return 1.f - 2.f / (__expf(2.f * x) + 1.f); }

// ---------------------------------------------------------------------------
// prep: bf16 casts + gate-reordered / combined decode weights
// gate reorder: n' = hcol*4 + gate  (gate 0..3 = i,f,g,o; source row = gate*H + hcol)
// ---------------------------------------------------------------------------
struct PrepArgs {
  const float *x, *W1, *W2, *W3, *Wh1, *Wc1, *Wx1, *Wh2, *Wc2, *Wx2;
  const float *rWih, *rWhh, *rbih, *rbhh, *pWih, *pWhh, *pbih, *pbhh;
  u16 *Xbf, *W1b, *W2b, *W3b, *Wh1b, *Wc1b, *Wx1b, *Wh2b, *Wc2b, *Wx2b;
  u16 *WcR, *WcatR, *pWR, *pWhhR;
  float *rbR, *pbR;
};

__global__ __launch_bounds__(256) void prep(PrepArgs p) {
  const int tid0 = blockIdx.x * 256 + threadIdx.x;
  const int stride = gridDim.x * 256;
  switch (blockIdx.y) {
    case 0: for (int i = tid0; i < 131072; i += stride) p.Xbf[i] = f2b(p.x[i]); break;
    case 1: for (int i = tid0; i < 65536;  i += stride) p.W1b[i] = f2b(p.W1[i]); break;
    case 2: for (int i = tid0; i < 262144; i += stride) p.W2b[i] = f2b(p.W2[i]); break;
    case 3: for (int i = tid0; i < 262144; i += stride) p.W3b[i] = f2b(p.W3[i]); break;
    case 4: for (int i = tid0; i < 262144; i += stride) p.Wh1b[i] = f2b(p.Wh1[i]); break;
    case 5: for (int i = tid0; i < 262144; i += stride) p.Wc1b[i] = f2b(p.Wc1[i]); break;
    case 6: for (int i = tid0; i < 262144; i += stride) p.Wx1b[i] = f2b(p.Wx1[i]); break;
    case 7: for (int i = tid0; i < 131072; i += stride) p.Wh2b[i] = f2b(p.Wh2[i]); break;
    case 8: for (int i = tid0; i < 131072; i += stride) p.Wc2b[i] = f2b(p.Wc2[i]); break;
    case 9: for (int i = tid0; i < 131072; i += stride) p.Wx2b[i] = f2b(p.Wx2[i]); break;
    case 10: // decode weights: combined (steps>=1) and concat (step 0), reordered
      for (int i = tid0; i < 262144; i += stride) {
        int n2 = i >> 8, k = i & 255;
        int srow = ((n2 & 3) << 8) + (n2 >> 2);
        float a = p.rWih[srow * 256 + k], b = p.rWhh[srow * 256 + k];
        p.WcR[i] = f2b(a + b);
        p.WcatR[n2 * 512 + k] = f2b(a);
        p.WcatR[n2 * 512 + 256 + k] = f2b(b);
      }
      break;
    case 11:
      for (int i = tid0; i < 1024; i += stride) {
        int srow = ((i & 3) << 8) + (i >> 2);
        p.rbR[i] = p.rbih[srow] + p.rbhh[srow];
      }
      break;
    case 12:
      for (int i = tid0; i < 32768; i += stride) {
        int n2 = i >> 8, k = i & 255;
        int srow = ((n2 & 3) << 5) + (n2 >> 2);
        p.pWR[i] = f2b(p.pWih[srow * 256 + k]);
      }
      break;
    case 13:
      for (int i = tid0; i < 4096; i += stride) {
        int n2 = i >> 5, k = i & 31;
        int srow = ((n2 & 3) << 5) + (n2 >> 2);
        p.pWhhR[i] = f2b(p.pWhh[srow * 32 + k]);
      }
      break;
    case 14:
      for (int i = tid0; i < 128; i += stride) {
        int srow = ((i & 3) << 5) + (i >> 2);
        p.pbR[i] = p.pbih[srow] + p.pbhh[srow];
      }
      break;
  }
}

// ---------------------------------------------------------------------------
// gemm_act: Y[1024,N] = act(X[1024,K] @ W[N,K]^T + bias), bf16 in, fp32 acc.
// ---------------------------------------------------------------------------
__global__ __launch_bounds__(256) void gemm_act(
    const u16* __restrict__ X, const u16* __restrict__ W,
    const float* __restrict__ bias,
    u16* __restrict__ Yb, float* __restrict__ Yf,
    int K, int ldo, int coloff, int leaky) {
  const int rt = blockIdx.x, ct = blockIdx.y;
  const int lane = threadIdx.x & 63, wave = threadIdx.x >> 6;
  const int m15 = lane & 15, q = lane >> 4, kq = q * 8;
  const int row = rt * 64 + wave * 16 + m15;
  f32x4 acc[4] = {};
  const u16* xp = X + (size_t)row * K + kq;
  for (int k0 = 0; k0 < K; k0 += 32) {
    bfrag a = *(const bfrag*)(xp + k0);
#pragma unroll
    for (int nt = 0; nt < 4; nt++) {
      const u16* wp = W + (size_t)(ct * 64 + nt * 16 + m15) * K + k0 + kq;
      acc[nt] = MFMA(a, *(const bfrag*)wp, acc[nt]);
    }
  }
#pragma unroll
  for (int nt = 0; nt < 4; nt++) {
    int col = ct * 64 + nt * 16 + m15;
    float bv = bias[col];
#pragma unroll
    for (int r = 0; r < 4; r++) {
      int orow = rt * 64 + wave * 16 + q * 4 + r;
      float v = acc[nt][r] + bv;
      if (leaky) v = v >= 0.f ? v : 0.2f * v;
      if (Yb) Yb[(size_t)orow * ldo + coloff + col] = f2b(v);
      else    Yf[(size_t)orow * ldo + coloff + col] = v;
    }
  }
}

// ---------------------------------------------------------------------------
// decode_step: used ONLY for step 0 (K=512 concat input).
// ---------------------------------------------------------------------------
__global__ __launch_bounds__(256) void decode_step(
    const u16* __restrict__ A, const u16* __restrict__ W,
    const float* __restrict__ rb,
    float* __restrict__ C, u16* __restrict__ Hout, int K) {
  __shared__ float g[64][128];
  const int rt = blockIdx.x, cg = blockIdx.y;
  const int lane = threadIdx.x & 63, wave = threadIdx.x >> 6;
  const int m15 = lane & 15, q = lane >> 4, kq = q * 8;
  const int row = rt * 64 + wave * 16 + m15;
  f32x4 acc[8] = {};
  const u16* ap = A + (size_t)row * K + kq;
  for (int k0 = 0; k0 < K; k0 += 32) {
    bfrag a = *(const bfrag*)(ap + k0);
#pragma unroll
    for (int nt = 0; nt < 8; nt++) {
      const u16* wp = W + (size_t)(cg * 128 + nt * 16 + m15) * K + k0 + kq;
      acc[nt] = MFMA(a, *(const bfrag*)wp, acc[nt]);
    }
  }
#pragma unroll
  for (int nt = 0; nt < 8; nt++)
#pragma unroll
    for (int r = 0; r < 4; r++)
      g[wave * 16 + q * 4 + r][nt * 16 + m15] = acc[nt][r];
  __syncthreads();
  for (int t = threadIdx.x; t < 2048; t += 256) {
    int rl = t >> 5, hc = t & 31;
    int grow = rt * 64 + rl, gcol = cg * 32 + hc;
    float gi = g[rl][hc * 4 + 0] + rb[cg * 128 + hc * 4 + 0];
    float gf = g[rl][hc * 4 + 1] + rb[cg * 128 + hc * 4 + 1];
    float gg = g[rl][hc * 4 + 2] + rb[cg * 128 + hc * 4 + 2];
    float go = g[rl][hc * 4 + 3] + rb[cg * 128 + hc * 4 + 3];
    size_t ci = (size_t)grow * 256 + gcol;
    float c = C[ci];
    float cn = ssig(gf) * c + ssig(gi) * stanh(gg);
    float hn = ssig(go) * stanh(cn);
    C[ci] = cn;
    Hout[ci] = f2b(hn);
  }
}

// ---------------------------------------------------------------------------
// decode_persist: steps 1..127 in ONE kernel. Block = 16 batch rows (row-
// independent recurrence => no inter-block communication). 1024 threads =
// 16 waves; wave w owns gate cols [w*64, w*64+64) (= hcols w*16..w*16+15).
// h double-buffered in LDS (1 barrier/step); c in registers; W streams from
// L2 (512 KB, XCD-resident). Gate->(row,hcol) regroup via per-wave LDS
// transpose (wave-coherent, no barrier).
// ---------------------------------------------------------------------------
__global__ __launch_bounds__(1024) void decode_persist(
    const u16* __restrict__ W,      // WcR [1024 gates][256]
    const float* __restrict__ rb,   // rbR [1024]
    const float* __restrict__ C0,   // CB  [1024][256] (c after step 0)
    u16* __restrict__ OUTS) {       // [128][1024][256]; OUTS[0] already done
  __shared__ u16 hbuf[2][16][264];        // 16.9 KB
  __shared__ float gbuf[16][32][20];      // 40 KB, per-wave [32 cols][20]
  const int tid = threadIdx.x;
  const int w = tid >> 6, lane = tid & 63;
  const int m15 = lane & 15, q = lane >> 4;
  const int rowg = blockIdx.x * 16;
  const int row = m15;

  // init: h_0 = OUTS[0] rows of this block
  for (int i = tid; i < 16 * 256; i += 1024) {
    int r = i >> 8, c = i & 255;
    hbuf[0][r][c] = OUTS[(size_t)(rowg + r) * 256 + c];
  }
  // lane owns (row=m15, hcols w*16 + p*8 + 2q + j), p=0..1, j=0..1
  float cst[2][2];
  float rbv[2][2][4];
#pragma unroll
  for (int p = 0; p < 2; p++)
#pragma unroll
    for (int j = 0; j < 2; j++) {
      int hc = w * 16 + p * 8 + 2 * q + j;
      cst[p][j] = C0[(size_t)(rowg + row) * 256 + hc];
#pragma unroll
      for (int g = 0; g < 4; g++) rbv[p][j][g] = rb[hc * 4 + g];
    }
  const u16* wp[4];
#pragma unroll
  for (int nt = 0; nt < 4; nt++)
    wp[nt] = W + (size_t)(w * 64 + nt * 16 + m15) * 256 + q * 8;
  __syncthreads();

  for (int s = 1; s < 128; s++) {
    const u16* hrow = hbuf[(s - 1) & 1][m15];
    u16* hn_ = &hbuf[s & 1][0][0];
    f32x4 acc[4] = {};
#pragma unroll
    for (int kt = 0; kt < 8; kt++) {
      bfrag a = *(const bfrag*)(hrow + kt * 32 + q * 8);
#pragma unroll
      for (int nt = 0; nt < 4; nt++)
        acc[nt] = MFMA(a, *(const bfrag*)(wp[nt] + kt * 32), acc[nt]);
    }
    u16* outp = OUTS + (size_t)s * (1024 * 256) + (size_t)(rowg + row) * 256;
#pragma unroll
    for (int p = 0; p < 2; p++) {
      // transpose frags 2p, 2p+1 via per-wave LDS (in-order DS, no barrier)
#pragma unroll
      for (int f = 0; f < 2; f++)
        *(f32x4*)&gbuf[w][f * 16 + m15][q * 4] = acc[2 * p + f];
      u16 hq[2];
#pragma unroll
      for (int j = 0; j < 2; j++) {
        int hp = 2 * q + j;  // hcol within pair (0..7)
        float gi = gbuf[w][hp * 4 + 0][row] + rbv[p][j][0];
        float gf = gbuf[w][hp * 4 + 1][row] + rbv[p][j][1];
        float gg = gbuf[w][hp * 4 + 2][row] + rbv[p][j][2];
        float go = gbuf[w][hp * 4 + 3][row] + rbv[p][j][3];
        float cn = ssig(gf) * cst[p][j] + ssig(gi) * stanh(gg);
        float hn = ssig(go) * stanh(cn);
        cst[p][j] = cn;
        hq[j] = f2b(hn);
      }
      unsigned pack = (unsigned)hq[0] | ((unsigned)hq[1] << 16);
      int hcb = w * 16 + p * 8 + 2 * q;
      *(unsigned*)&hn_[row * 264 + hcb] = pack;
      *(unsigned*)(outp + hcb) = pack;
    }
    __syncthreads();
  }
}

// ---------------------------------------------------------------------------
// predictor2: 64 blocks x 256 thr (4 waves), block = 16 batch rows, all 128
// steps. Wave w owns pred-gate cols [w*32, w*32+32) (= hcols w*8..w*8+7);
// weights register-resident (18 MFMAs/step/wave). 2 barriers/step.
// ---------------------------------------------------------------------------
__global__ __launch_bounds__(256) void predictor2(
    const u16* __restrict__ OUTS, const u16* __restrict__ pW,
    const u16* __restrict__ pWhh, const float* __restrict__ pb,
    float* __restrict__ out) {
  __shared__ u16 hs[2][16][40];
  __shared__ float ys[16][36];
  __shared__ float smv[16], siv[16];
  __shared__ float gbuf[4][16][20];
  const int tid = threadIdx.x, w = tid >> 6, lane = tid & 63;
  const int m15 = lane & 15, q = lane >> 4;
  const int rowg = blockIdx.x * 16;

  bfrag WX[8][2], WH[2];
  float pbv[2][4];
#pragma unroll
  for (int nt = 0; nt < 2; nt++) {
    int n = w * 32 + nt * 16 + m15;
#pragma unroll
    for (int kt = 0; kt < 8; kt++)
      WX[kt][nt] = *(const bfrag*)(pW + (size_t)n * 256 + kt * 32 + q * 8);
    WH[nt] = *(const bfrag*)(pWhh + (size_t)n * 32 + q * 8);
  }
  float cst[2] = {0.f, 0.f};
#pragma unroll
  for (int nt = 0; nt < 2; nt++) {
    int hc = w * 8 + nt * 4 + q;
#pragma unroll
    for (int g = 0; g < 4; g++) pbv[nt][g] = pb[hc * 4 + g];
  }
  for (int i = tid; i < 2 * 16 * 40; i += 256) (&hs[0][0][0])[i] = 0;
  __syncthreads();

  for (int s = 0; s < 128; s++) {
    const u16* xs = OUTS + (size_t)s * (1024 * 256) + (size_t)(rowg + m15) * 256 + q * 8;
    f32x4 a0 = {}, a1 = {};
#pragma unroll
    for (int kt = 0; kt < 8; kt++) {
      bfrag a = *(const bfrag*)(xs + kt * 32);
      a0 = MFMA(a, WX[kt][0], a0);
      a1 = MFMA(a, WX[kt][1], a1);
    }
    {
      bfrag ah = *(const bfrag*)&hs[s & 1][m15][q * 8];
      a0 = MFMA(ah, WH[0], a0);
      a1 = MFMA(ah, WH[1], a1);
    }
    float hv[2];
#pragma unroll
    for (int nt = 0; nt < 2; nt++) {
      *(f32x4*)&gbuf[w][m15][q * 4] = nt ? a1 : a0;  // per-wave, in-order DS
      int hc = w * 8 + nt * 4 + q;
      float gi = gbuf[w][q * 4 + 0][m15] + pbv[nt][0];
      float gf = gbuf[w][q * 4 + 1][m15] + pbv[nt][1];
      float gg = gbuf[w][q * 4 + 2][m15] + pbv[nt][2];
      float go = gbuf[w][q * 4 + 3][m15] + pbv[nt][3];
      float cn = ssig(gf) * cst[nt] + ssig(gi) * stanh(gg);
      float hn = ssig(go) * stanh(cn);
      cst[nt] = cn; hv[nt] = hn;
      hs[(s + 1) & 1][m15][hc] = f2b(hn);
      ys[m15][hc] = hn;
    }
    __syncthreads();
    if (lane < 4) {  // wave w reduces rows w*4..w*4+3
      int r = w * 4 + lane;
      f32x4 vv[8];
#pragma unroll
      for (int i = 0; i < 8; i++) vv[i] = *(f32x4*)&ys[r][i * 4];
      float m = vv[0][0];
#pragma unroll
      for (int i = 0; i < 8; i++)
#pragma unroll
        for (int e = 0; e < 4; e++)
          if (i * 4 + e < 31) m = fmaxf(m, vv[i][e]);
      float ssum = 0.f;
#pragma unroll
      for (int i = 0; i < 8; i++)
#pragma unroll
        for (int e = 0; e < 4; e++)
          if (i * 4 + e < 31) ssum += __expf(vv[i][e] - m);
      smv[r] = m; siv[r] = 1.f / ssum;
    }
    __syncthreads();
#pragma unroll
    for (int nt = 0; nt < 2; nt++) {
      int hc = w * 8 + nt * 4 + q;
      float v = (hc < 31) ? __expf(hv[nt] - smv[m15]) * siv[m15] : ssig(hv[nt]);
      out[(size_t)(rowg + m15) * 4096 + s * 32 + hc] = v;
    }
  }
}

// ---------------------------------------------------------------------------
extern "C" void kernel_launch(void* const* d_in, const int* in_sizes, int n_in,
                              void* d_out, int out_size, void* d_ws, size_t ws_size,
                              hipStream_t stream) {
  (void)in_sizes; (void)n_in; (void)out_size; (void)ws_size;
  const float* x    = (const float*)d_in[0];
  const float* W1   = (const float*)d_in[1];
  const float* b1   = (const float*)d_in[2];
  const float* W2   = (const float*)d_in[3];
  const float* b2   = (const float*)d_in[4];
  const float* W3   = (const float*)d_in[5];
  const float* b3   = (const float*)d_in[6];
  const float* Wh1  = (const float*)d_in[7];
  const float* bh1  = (const float*)d_in[8];
  const float* Wh2  = (const float*)d_in[9];
  const float* bh2  = (const float*)d_in[10];
  const float* Wc1  = (const float*)d_in[11];
  const float* bc1  = (const float*)d_in[12];
  const float* Wc2  = (const float*)d_in[13];
  const float* bc2  = (const float*)d_in[14];
  const float* Wx1  = (const float*)d_in[15];
  const float* bx1  = (const float*)d_in[16];
  const float* Wx2  = (const float*)d_in[17];
  const float* bx2  = (const float*)d_in[18];
  const float* rWih = (const float*)d_in[19];
  const float* rWhh = (const float*)d_in[20];
  const float* rbih = (const float*)d_in[21];
  const float* rbhh = (const float*)d_in[22];
  const float* pWih = (const float*)d_in[23];
  const float* pWhh = (const float*)d_in[24];
  const float* pbih = (const float*)d_in[25];
  const float* pbhh = (const float*)d_in[26];

  char* w = (char*)d_ws;
  auto alloc = [&](size_t bytes) -> char* {
    char* p = w;
    w += (bytes + 255) & ~(size_t)255;
    return p;
  };
  u16* Xbf  = (u16*)alloc(1024 * 128 * 2);
  u16* T1   = (u16*)alloc(1024 * 512 * 2);
  u16* T2   = (u16*)alloc(1024 * 512 * 2);
  u16* T3   = (u16*)alloc(1024 * 512 * 2);
  u16* TH   = (u16*)alloc(1024 * 512 * 2);
  u16* TC   = (u16*)alloc(1024 * 512 * 2);
  u16* TX   = (u16*)alloc(1024 * 512 * 2);
  u16* X0H  = (u16*)alloc(1024 * 512 * 2);  // cols 0..255 = x0, 256..511 = h
  float* CB = (float*)alloc(1024 * 256 * 4);
  u16* OUTS = (u16*)alloc((size_t)128 * 1024 * 256 * 2);
  u16* W1b  = (u16*)alloc(512 * 128 * 2);
  u16* W2b  = (u16*)alloc(512 * 512 * 2);
  u16* W3b  = (u16*)alloc(512 * 512 * 2);
  u16* Wh1b = (u16*)alloc(512 * 512 * 2);
  u16* Wc1b = (u16*)alloc(512 * 512 * 2);
  u16* Wx1b = (u16*)alloc(512 * 512 * 2);
  u16* Wh2b = (u16*)alloc(256 * 512 * 2);
  u16* Wc2b = (u16*)alloc(256 * 512 * 2);
  u16* Wx2b = (u16*)alloc(256 * 512 * 2);
  u16* WcR  = (u16*)alloc(1024 * 256 * 2);
  u16* WcatR= (u16*)alloc(1024 * 512 * 2);
  float* rbR = (float*)alloc(1024 * 4);
  u16* pWR  = (u16*)alloc(128 * 256 * 2);
  u16* pWhhR= (u16*)alloc(128 * 32 * 2);
  float* pbR = (float*)alloc(128 * 4);

  PrepArgs pa;
  pa.x = x; pa.W1 = W1; pa.W2 = W2; pa.W3 = W3; pa.Wh1 = Wh1; pa.Wc1 = Wc1; pa.Wx1 = Wx1;
  pa.Wh2 = Wh2; pa.Wc2 = Wc2; pa.Wx2 = Wx2;
  pa.rWih = rWih; pa.rWhh = rWhh; pa.rbih = rbih; pa.rbhh = rbhh;
  pa.pWih = pWih; pa.pWhh = pWhh; pa.pbih = pbih; pa.pbhh = pbhh;
  pa.Xbf = Xbf; pa.W1b = W1b; pa.W2b = W2b; pa.W3b = W3b; pa.Wh1b = Wh1b;
  pa.Wc1b = Wc1b; pa.Wx1b = Wx1b; pa.Wh2b = Wh2b; pa.Wc2b = Wc2b; pa.Wx2b = Wx2b;
  pa.WcR = WcR; pa.WcatR = WcatR; pa.pWR = pWR; pa.pWhhR = pWhhR;
  pa.rbR = rbR; pa.pbR = pbR;
  prep<<<dim3(32, 15), 256, 0, stream>>>(pa);

  // MLP + heads
  gemm_act<<<dim3(16, 8), 256, 0, stream>>>(Xbf, W1b, b1, T1, nullptr, 128, 512, 0, 1);
  gemm_act<<<dim3(16, 8), 256, 0, stream>>>(T1, W2b, b2, T2, nullptr, 512, 512, 0, 1);
  gemm_act<<<dim3(16, 8), 256, 0, stream>>>(T2, W3b, b3, T3, nullptr, 512, 512, 0, 1);
  gemm_act<<<dim3(16, 8), 256, 0, stream>>>(T3, Wh1b, bh1, TH, nullptr, 512, 512, 0, 1);
  gemm_act<<<dim3(16, 8), 256, 0, stream>>>(T3, Wc1b, bc1, TC, nullptr, 512, 512, 0, 1);
  gemm_act<<<dim3(16, 8), 256, 0, stream>>>(T3, Wx1b, bx1, TX, nullptr, 512, 512, 0, 1);
  gemm_act<<<dim3(16, 4), 256, 0, stream>>>(TH, Wh2b, bh2, X0H, nullptr, 512, 512, 256, 0); // h
  gemm_act<<<dim3(16, 4), 256, 0, stream>>>(TC, Wc2b, bc2, nullptr, CB, 512, 256, 0, 0);    // c (fp32)
  gemm_act<<<dim3(16, 4), 256, 0, stream>>>(TX, Wx2b, bx2, X0H, nullptr, 512, 512, 0, 0);   // x0

  // decode LSTM: step 0 (K=512 concat), then persistent steps 1..127
  decode_step<<<dim3(16, 8), 256, 0, stream>>>(X0H, WcatR, rbR, CB, OUTS, 512);
  decode_persist<<<64, 1024, 0, stream>>>(WcR, rbR, CB, OUTS);

  // predictor LSTM + fused softmax/sigmoid epilogue
  predictor2<<<64, 256, 0, stream>>>(OUTS, pWR, pWhhR, pbR, (float*)d_out);
}